// Round 10
// baseline (35.724 us; speedup 1.0000x reference)
//
#include <hip/hip_runtime.h>

static constexpr float INV_SQRT2 = 0.70710678118654752f;
static constexpr float INV_SQRT3 = 0.57735026918962576f;
static constexpr float SQRT2     = 1.41421356237309505f;
static constexpr float INV_SQRT6 = 0.40824829046386302f;

static constexpr int W_GRAPHS = 8;  // graphs per wave

// branchless fast tanh: 1 - 2/(exp(2x)+1); exact at +/-inf, err ~1e-7
__device__ __forceinline__ float fast_tanh(float x) {
    const float e = __builtin_amdgcn_exp2f(x * 2.8853900817779268f); // 2*log2(e)
    const float r = __builtin_amdgcn_rcpf(e + 1.0f);
    return fmaf(-2.0f, r, 1.0f);
}

// sign-gated coefficient: relu(t*k)*fw == t * (t>0 ? pos_part : neg_part)
__device__ __forceinline__ float gate_p(float k, float fw) { return k > 0.f ? k * fw : 0.f; }
__device__ __forceinline__ float gate_n(float k, float fw) { return k < 0.f ? k * fw : 0.f; }

// Fused single-dispatch kernel; wave owns 8 graphs, walks union node range
// with a 4x-unrolled main loop (8 loads in flight before compute) to cover
// global-load latency with in-wave ILP. NOTE: no min-waves launch bound —
// round 9 showed (256,8) pins VGPR=32 and spills 14.6 MB to scratch.
__global__ __launch_bounds__(256) void e3nn_fused(
    const int*   __restrict__ z,
    const float* __restrict__ pos,
    const int*   __restrict__ batch,
    const float* __restrict__ w_tp,
    const float* __restrict__ fc_w,
    const float* __restrict__ fc_b,
    float*       __restrict__ out,
    int n, int n_graphs)
{
    const int lane = threadIdx.x & 63;
    const int wave = (blockIdx.x * blockDim.x + threadIdx.x) >> 6;
    const int g0   = wave * W_GRAPHS;
    if (g0 >= n_graphs) return;

    // ---- uniform weight prep (once per wave) ----
    const float kA0 = w_tp[0] * INV_SQRT2;
    const float kA1 = w_tp[1] * INV_SQRT2;
    const float kB0 = w_tp[2] * (INV_SQRT3 * INV_SQRT2);
    const float kB1 = w_tp[3] * (INV_SQRT3 * INV_SQRT2);
    const float c0  = (w_tp[4] + w_tp[6]) * INV_SQRT2;
    const float c1  = (w_tp[5] + w_tp[7]) * INV_SQRT2;
    const float wE  = w_tp[8];
    const float fw0 = fc_w[0], fw1 = fc_w[1];
    const float fb  = fc_b[0];

    const float P0 = gate_p(c0, fc_w[2]) + gate_p(c1, fc_w[5]);
    const float N0 = gate_n(c0, fc_w[2]) + gate_n(c1, fc_w[5]);
    const float P1 = gate_p(c0, fc_w[3]) + gate_p(c1, fc_w[6]);
    const float N1 = gate_n(c0, fc_w[3]) + gate_n(c1, fc_w[6]);
    const float P2 = gate_p(c0, fc_w[4]) + gate_p(c1, fc_w[7]);
    const float N2 = gate_n(c0, fc_w[4]) + gate_n(c1, fc_w[7]);
    const float k8  = wE * SQRT2,     k11 = wE * INV_SQRT2, k12 = wE * INV_SQRT6;
    const float P8  = gate_p(k8,  fc_w[8]),  N8  = gate_n(k8,  fc_w[8]);
    const float P9  = gate_p(k8,  fc_w[9]),  N9  = gate_n(k8,  fc_w[9]);
    const float P10 = gate_p(k8,  fc_w[10]), N10 = gate_n(k8,  fc_w[10]);
    const float P11 = gate_p(k11, fc_w[11]), N11 = gate_n(k11, fc_w[11]);
    const float P12 = gate_p(k12, fc_w[12]), N12 = gate_n(k12, fc_w[12]);

    // ---- per-lane lower_bound(batch, g0 + min(lane,8)) ----
    const int tl     = (lane < W_GRAPHS) ? lane : W_GRAPHS;
    const int target = g0 + tl;
    unsigned p2 = 1;
    while (p2 < (unsigned)n) p2 <<= 1;
    int bval = 0;
    for (unsigned step = p2 >> 1; step > 0; step >>= 1) {
        const unsigned cand = (unsigned)bval + step;
        if (cand <= (unsigned)n && batch[cand - 1] < target) bval = (int)cand;
    }

    // converged shuffles: distribute boundaries
    const int nb = __shfl_down(bval, 1);   // lane l: bnd[g0+l+1] (valid l<=7)
    const int B0 = __shfl(bval, 0), B1 = __shfl(bval, 1);
    const int B2 = __shfl(bval, 2), B3 = __shfl(bval, 3);
    const int B4 = __shfl(bval, 4), B5 = __shfl(bval, 5);
    const int B6 = __shfl(bval, 6), B7 = __shfl(bval, 7);
    const int B8 = __shfl(bval, 8);

    float a0 = 0.f, a1 = 0.f, a2 = 0.f, a3 = 0.f;
    float a4 = 0.f, a5 = 0.f, a6 = 0.f, a7 = 0.f;

    // per-node compute + route (y zeroed for inactive lanes)
    auto body = [&](int i, float sc, float v0, float v1, float v2) {
        const float v00 = v0 * v0, v11 = v1 * v1, v22 = v2 * v2;
        const float ss  = sc * sc;
        const float dr  = v00 + v11 + v22;

        float acc = fb;
        const float x0 = fmaf(ss, kA0, dr * kB0);
        const float x1 = fmaf(ss, kA1, dr * kB1);
        acc = fmaf(fmaxf(x0, 0.f), fw0, acc);
        acc = fmaf(fmaxf(x1, 0.f), fw1, acc);

        const float sv0 = sc * v0, sv1 = sc * v1, sv2 = sc * v2;
        acc = fmaf(sv0, (sv0 > 0.f ? P0 : N0), acc);
        acc = fmaf(sv1, (sv1 > 0.f ? P1 : N1), acc);
        acc = fmaf(sv2, (sv2 > 0.f ? P2 : N2), acc);

        const float t8 = v0 * v1, t9 = v1 * v2, t10 = v0 * v2;
        acc = fmaf(t8,  (t8  > 0.f ? P8  : N8 ), acc);
        acc = fmaf(t9,  (t9  > 0.f ? P9  : N9 ), acc);
        acc = fmaf(t10, (t10 > 0.f ? P10 : N10), acc);

        const float t11 = v00 - v11;
        acc = fmaf(t11, (t11 > 0.f ? P11 : N11), acc);
        const float t12 = (v22 - v00) + (v22 - v11);
        acc = fmaf(t12, (t12 > 0.f ? P12 : N12), acc);

        float y = fast_tanh(acc);
        y = (i < B8) ? y : 0.f;   // inactive lanes contribute nothing

        const bool ge1 = i >= B1, ge2 = i >= B2, ge3 = i >= B3;
        const bool ge4 = i >= B4, ge5 = i >= B5, ge6 = i >= B6;
        const bool ge7 = i >= B7;
        a0 += (!ge1)        ? y : 0.f;
        a1 += (ge1 && !ge2) ? y : 0.f;
        a2 += (ge2 && !ge3) ? y : 0.f;
        a3 += (ge3 && !ge4) ? y : 0.f;
        a4 += (ge4 && !ge5) ? y : 0.f;
        a5 += (ge5 && !ge6) ? y : 0.f;
        a6 += (ge6 && !ge7) ? y : 0.f;
        a7 += (ge7)         ? y : 0.f;
    };

#pragma unroll 1
    for (int base = B0; base < B8; base += 256) {
        const int i0 = base + lane;
        const int i1 = i0 + 64;
        const int i2 = i1 + 64;
        const int i3 = i2 + 64;

        // cluster all loads first: up to 8 loads in flight per wave
        float s0 = 0.f, p00 = 0.f, p01 = 0.f, p02 = 0.f;
        float s1 = 0.f, p10 = 0.f, p11 = 0.f, p12v = 0.f;
        float s2 = 0.f, p20 = 0.f, p21 = 0.f, p22 = 0.f;
        float s3 = 0.f, p30 = 0.f, p31 = 0.f, p32 = 0.f;
        if (i0 < B8) { s0 = (float)z[i0]; p00 = pos[3*i0]; p01 = pos[3*i0+1]; p02 = pos[3*i0+2]; }
        if (i1 < B8) { s1 = (float)z[i1]; p10 = pos[3*i1]; p11 = pos[3*i1+1]; p12v = pos[3*i1+2]; }
        if (i2 < B8) { s2 = (float)z[i2]; p20 = pos[3*i2]; p21 = pos[3*i2+1]; p22 = pos[3*i2+2]; }
        if (i3 < B8) { s3 = (float)z[i3]; p30 = pos[3*i3]; p31 = pos[3*i3+1]; p32 = pos[3*i3+2]; }

        body(i0, s0, p00, p01, p02);
        body(i1, s1, p10, p11, p12v);
        body(i2, s2, p20, p21, p22);
        body(i3, s3, p30, p31, p32);
    }

    // one butterfly reduction per accumulator (epilogue only, converged)
#pragma unroll
    for (int off = 32; off >= 1; off >>= 1) {
        a0 += __shfl_xor(a0, off);
        a1 += __shfl_xor(a1, off);
        a2 += __shfl_xor(a2, off);
        a3 += __shfl_xor(a3, off);
        a4 += __shfl_xor(a4, off);
        a5 += __shfl_xor(a5, off);
        a6 += __shfl_xor(a6, off);
        a7 += __shfl_xor(a7, off);
    }

    // lanes 0..7 write the 8 outputs (nb computed while converged)
    if (lane < W_GRAPHS && g0 + lane < n_graphs) {
        float sel = (lane == 0) ? a0
                  : (lane == 1) ? a1
                  : (lane == 2) ? a2
                  : (lane == 3) ? a3
                  : (lane == 4) ? a4
                  : (lane == 5) ? a5
                  : (lane == 6) ? a6
                  :               a7;
        const float c = (float)(nb - bval);
        out[g0 + lane] = sel / fmaxf(c, 1.0f);
    }
}

extern "C" void kernel_launch(void* const* d_in, const int* in_sizes, int n_in,
                              void* d_out, int out_size, void* d_ws, size_t ws_size,
                              hipStream_t stream) {
    const int*   z     = (const int*)d_in[0];
    const float* pos   = (const float*)d_in[1];
    const int*   batch = (const int*)d_in[2];
    const float* w_tp  = (const float*)d_in[3];
    const float* fc_w  = (const float*)d_in[4];
    const float* fc_b  = (const float*)d_in[5];

    float* out = (float*)d_out;
    const int n        = in_sizes[0];
    const int n_graphs = out_size;

    const int waves = (n_graphs + W_GRAPHS - 1) / W_GRAPHS;
    const int blocks = (waves * 64 + 255) / 256;
    e3nn_fused<<<blocks, 256, 0, stream>>>(z, pos, batch, w_tp, fc_w, fc_b,
                                           out, n, n_graphs);
}

// Round 12
// 31.602 us; speedup vs baseline: 1.1304x; 1.1304x over previous
//
#include <hip/hip_runtime.h>

static constexpr float INV_SQRT2 = 0.70710678118654752f;
static constexpr float INV_SQRT3 = 0.57735026918962576f;
static constexpr float SQRT2     = 1.41421356237309505f;
static constexpr float INV_SQRT6 = 0.40824829046386302f;

static constexpr int W_GRAPHS = 8;  // graphs per wave

// branchless fast tanh: 1 - 2/(exp(2x)+1); exact at +/-inf, err ~1e-7
__device__ __forceinline__ float fast_tanh(float x) {
    const float e = __builtin_amdgcn_exp2f(x * 2.8853900817779268f); // 2*log2(e)
    const float r = __builtin_amdgcn_rcpf(e + 1.0f);
    return fmaf(-2.0f, r, 1.0f);
}

__device__ __forceinline__ float gate_p(float k, float fw) { return k > 0.f ? k * fw : 0.f; }
__device__ __forceinline__ float gate_n(float k, float fw) { return k < 0.f ? k * fw : 0.f; }

struct F3 { float x, y, zc; };

// Fused single-dispatch kernel. Wave owns 8 graphs; seeded lower_bound for
// boundaries (16 probes + verify, full-search fallback); main loop does
// 2 nodes/lane/iter (int2 + 2x dwordx3 loads) with depth-1 register
// prefetch behind a WAVE-UNIFORM branch.
// FIX (r11): lastEven = (B8-1)&~1. With the old (B8-2)&~1, odd B8 clamped
// the last valid node's load to the wrong pair -> absmax 4.3e-2. For odd
// B8 the pair (B8-1, B8) is safe: n is even, so odd B8 < n strictly.
__global__ __launch_bounds__(256, 6) void e3nn_fused(
    const int*   __restrict__ z,
    const float* __restrict__ pos,
    const int*   __restrict__ batch,
    const float* __restrict__ w_tp,
    const float* __restrict__ fc_w,
    const float* __restrict__ fc_b,
    float*       __restrict__ out,
    int n, int n_graphs)
{
    const int lane = threadIdx.x & 63;
    const int wave = (blockIdx.x * blockDim.x + threadIdx.x) >> 6;
    const int g0   = wave * W_GRAPHS;
    if (g0 >= n_graphs) return;

    // ---- uniform weight prep ----
    const float kA0 = w_tp[0] * INV_SQRT2;
    const float kA1 = w_tp[1] * INV_SQRT2;
    const float kB0 = w_tp[2] * (INV_SQRT3 * INV_SQRT2);
    const float kB1 = w_tp[3] * (INV_SQRT3 * INV_SQRT2);
    const float c0  = (w_tp[4] + w_tp[6]) * INV_SQRT2;
    const float c1  = (w_tp[5] + w_tp[7]) * INV_SQRT2;
    const float wE  = w_tp[8];
    const float fw0 = fc_w[0], fw1 = fc_w[1];
    const float fb  = fc_b[0];

    const float P0 = gate_p(c0, fc_w[2]) + gate_p(c1, fc_w[5]);
    const float N0 = gate_n(c0, fc_w[2]) + gate_n(c1, fc_w[5]);
    const float P1 = gate_p(c0, fc_w[3]) + gate_p(c1, fc_w[6]);
    const float N1 = gate_n(c0, fc_w[3]) + gate_n(c1, fc_w[6]);
    const float P2 = gate_p(c0, fc_w[4]) + gate_p(c1, fc_w[7]);
    const float N2 = gate_n(c0, fc_w[4]) + gate_n(c1, fc_w[7]);
    const float k8  = wE * SQRT2,     k11 = wE * INV_SQRT2, k12 = wE * INV_SQRT6;
    const float P8  = gate_p(k8,  fc_w[8]),  N8  = gate_n(k8,  fc_w[8]);
    const float P9  = gate_p(k8,  fc_w[9]),  N9  = gate_n(k8,  fc_w[9]);
    const float P10 = gate_p(k8,  fc_w[10]), N10 = gate_n(k8,  fc_w[10]);
    const float P11 = gate_p(k11, fc_w[11]), N11 = gate_n(k11, fc_w[11]);
    const float P12 = gate_p(k12, fc_w[12]), N12 = gate_n(k12, fc_w[12]);

    // ---- seeded lower_bound(batch, target), window +/-32768 ----
    const int tl     = (lane < W_GRAPHS) ? lane : W_GRAPHS;
    const int target = g0 + tl;
    long long seed = (long long)target * 64 - 32768;
    int lo = seed < 0 ? 0 : (seed > n ? n : (int)seed);
    int bval = lo;
    #pragma unroll 1
    for (int step = 32768; step > 0; step >>= 1) {
        const int cand = bval + step;
        if (cand <= n && batch[cand - 1] < target) bval = cand;
    }
    {   // verify; fall back to full search if the window assumption failed
        const bool ok = (bval == 0 || batch[bval - 1] < target) &&
                        (bval >= n || batch[bval] >= target);
        if (!__all(ok)) {
            unsigned p2 = 1;
            while (p2 < (unsigned)n) p2 <<= 1;
            bval = 0;
            for (unsigned step = p2; step > 0; step >>= 1) {
                const unsigned cand = (unsigned)bval + step;
                if (cand <= (unsigned)n && batch[cand - 1] < target) bval = (int)cand;
            }
        }
    }

    // converged shuffles: distribute boundaries
    const int nb = __shfl_down(bval, 1);
    const int B0 = __shfl(bval, 0), B1 = __shfl(bval, 1);
    const int B2 = __shfl(bval, 2), B3 = __shfl(bval, 3);
    const int B4 = __shfl(bval, 4), B5 = __shfl(bval, 5);
    const int B6 = __shfl(bval, 6), B7 = __shfl(bval, 7);
    const int B8 = __shfl(bval, 8);

    float a0 = 0.f, a1 = 0.f, a2 = 0.f, a3 = 0.f;
    float a4 = 0.f, a5 = 0.f, a6 = 0.f, a7 = 0.f;

    auto body = [&](int i, float sc, float v0, float v1, float v2) {
        const float v00 = v0 * v0, v11 = v1 * v1, v22 = v2 * v2;
        const float ss  = sc * sc;
        const float dr  = v00 + v11 + v22;

        float acc = fb;
        const float x0 = fmaf(ss, kA0, dr * kB0);
        const float x1 = fmaf(ss, kA1, dr * kB1);
        acc = fmaf(fmaxf(x0, 0.f), fw0, acc);
        acc = fmaf(fmaxf(x1, 0.f), fw1, acc);

        const float sv0 = sc * v0, sv1 = sc * v1, sv2 = sc * v2;
        acc = fmaf(sv0, (sv0 > 0.f ? P0 : N0), acc);
        acc = fmaf(sv1, (sv1 > 0.f ? P1 : N1), acc);
        acc = fmaf(sv2, (sv2 > 0.f ? P2 : N2), acc);

        const float t8 = v0 * v1, t9 = v1 * v2, t10 = v0 * v2;
        acc = fmaf(t8,  (t8  > 0.f ? P8  : N8 ), acc);
        acc = fmaf(t9,  (t9  > 0.f ? P9  : N9 ), acc);
        acc = fmaf(t10, (t10 > 0.f ? P10 : N10), acc);

        const float t11 = v00 - v11;
        acc = fmaf(t11, (t11 > 0.f ? P11 : N11), acc);
        const float t12 = (v22 - v00) + (v22 - v11);
        acc = fmaf(t12, (t12 > 0.f ? P12 : N12), acc);

        float y = fast_tanh(acc);
        // valid iff B0 <= i < B8
        y = ((unsigned)(i - B0) < (unsigned)(B8 - B0)) ? y : 0.f;

        const bool ge1 = i >= B1, ge2 = i >= B2, ge3 = i >= B3;
        const bool ge4 = i >= B4, ge5 = i >= B5, ge6 = i >= B6;
        const bool ge7 = i >= B7;
        a0 += (!ge1)        ? y : 0.f;
        a1 += (ge1 && !ge2) ? y : 0.f;
        a2 += (ge2 && !ge3) ? y : 0.f;
        a3 += (ge3 && !ge4) ? y : 0.f;
        a4 += (ge4 && !ge5) ? y : 0.f;
        a5 += (ge5 && !ge6) ? y : 0.f;
        a6 += (ge6 && !ge7) ? y : 0.f;
        a7 += (ge7)         ? y : 0.f;
    };

    if (B0 < B8) {
        const int first = B0 & ~1;            // even start
        // pair-start covering the LAST valid node (fix: was (B8-2)&~1).
        // B8 even -> B8-2 (pair in-bounds); B8 odd -> B8-1, pair reads
        // index B8 which is < n since n is even.
        const int lastEven = (B8 - 1) & ~1;

        auto pidx = [&](int ii) {
            int c = ii < lastEven ? ii : lastEven;
            return c < 0 ? 0 : c;
        };

        // prefetch iteration 0
        int ic = pidx(first + 2 * lane);
        int2 zz = *reinterpret_cast<const int2*>(z + ic);
        F3  pa  = *reinterpret_cast<const F3*>(pos + 3 * ic);
        F3  pb  = *reinterpret_cast<const F3*>(pos + 3 * ic + 3);

        #pragma unroll 1
        for (int base = first; base < B8; base += 128) {
            int2 zzn = {0, 0};
            F3 pan = {0.f, 0.f, 0.f}, pbn = {0.f, 0.f, 0.f};
            const bool more = (base + 128) < B8;            // wave-uniform
            if (more) {
                const int jc = pidx(base + 128 + 2 * lane);
                zzn = *reinterpret_cast<const int2*>(z + jc);
                pan = *reinterpret_cast<const F3*>(pos + 3 * jc);
                pbn = *reinterpret_cast<const F3*>(pos + 3 * jc + 3);
            }
            const int i0 = base + 2 * lane;
            body(i0,     (float)zz.x, pa.x, pa.y, pa.zc);
            body(i0 + 1, (float)zz.y, pb.x, pb.y, pb.zc);
            zz = zzn; pa = pan; pb = pbn;
        }
    }

    // butterfly reduction (converged)
#pragma unroll
    for (int off = 32; off >= 1; off >>= 1) {
        a0 += __shfl_xor(a0, off);
        a1 += __shfl_xor(a1, off);
        a2 += __shfl_xor(a2, off);
        a3 += __shfl_xor(a3, off);
        a4 += __shfl_xor(a4, off);
        a5 += __shfl_xor(a5, off);
        a6 += __shfl_xor(a6, off);
        a7 += __shfl_xor(a7, off);
    }

    if (lane < W_GRAPHS && g0 + lane < n_graphs) {
        float sel = (lane == 0) ? a0
                  : (lane == 1) ? a1
                  : (lane == 2) ? a2
                  : (lane == 3) ? a3
                  : (lane == 4) ? a4
                  : (lane == 5) ? a5
                  : (lane == 6) ? a6
                  :               a7;
        const float c = (float)(nb - bval);
        out[g0 + lane] = sel / fmaxf(c, 1.0f);
    }
}

extern "C" void kernel_launch(void* const* d_in, const int* in_sizes, int n_in,
                              void* d_out, int out_size, void* d_ws, size_t ws_size,
                              hipStream_t stream) {
    const int*   z     = (const int*)d_in[0];
    const float* pos   = (const float*)d_in[1];
    const int*   batch = (const int*)d_in[2];
    const float* w_tp  = (const float*)d_in[3];
    const float* fc_w  = (const float*)d_in[4];
    const float* fc_b  = (const float*)d_in[5];

    float* out = (float*)d_out;
    const int n        = in_sizes[0];
    const int n_graphs = out_size;

    const int waves  = (n_graphs + W_GRAPHS - 1) / W_GRAPHS;
    const int blocks = (waves * 64 + 255) / 256;
    e3nn_fused<<<blocks, 256, 0, stream>>>(z, pos, batch, w_tp, fc_w, fc_b,
                                           out, n, n_graphs);
}

// Round 13
// 26.310 us; speedup vs baseline: 1.3578x; 1.2012x over previous
//
#include <hip/hip_runtime.h>

static constexpr float INV_SQRT2 = 0.70710678118654752f;
static constexpr float INV_SQRT3 = 0.57735026918962576f;
static constexpr float SQRT2     = 1.41421356237309505f;
static constexpr float INV_SQRT6 = 0.40824829046386302f;

static constexpr int W_GRAPHS = 8;   // graphs per wave
static constexpr int B_GRAPHS = 32;  // graphs per block (4 waves)

// branchless fast tanh: 1 - 2/(exp(2x)+1); exact at +/-inf, err ~1e-7
__device__ __forceinline__ float fast_tanh(float x) {
    const float e = __builtin_amdgcn_exp2f(x * 2.8853900817779268f); // 2*log2(e)
    const float r = __builtin_amdgcn_rcpf(e + 1.0f);
    return fmaf(-2.0f, r, 1.0f);
}

__device__ __forceinline__ float gate_p(float k, float fw) { return k > 0.f ? k * fw : 0.f; }
__device__ __forceinline__ float gate_n(float k, float fw) { return k < 0.f ? k * fw : 0.f; }

// Fused single-dispatch kernel. Block owns 32 graphs; WAVE 0 runs the
// 22-probe lower_bound once for all 33 boundaries (one serial dependent-load
// chain per BLOCK, not per wave) and shares via LDS. Each wave then walks its
// 8 graphs' union node range with the simple 1-node/lane loop (empirically
// fastest: in-wave ILP variants r9-r12 all regressed vs this structure).
__global__ __launch_bounds__(256) void e3nn_fused(
    const int*   __restrict__ z,
    const float* __restrict__ pos,
    const int*   __restrict__ batch,
    const float* __restrict__ w_tp,
    const float* __restrict__ fc_w,
    const float* __restrict__ fc_b,
    float*       __restrict__ out,
    int n, int n_graphs)
{
    const int tid  = threadIdx.x;
    const int wid  = tid >> 6;
    const int lane = tid & 63;
    const int bg0  = blockIdx.x * B_GRAPHS;
    if (bg0 >= n_graphs) return;

    __shared__ int sbnd[B_GRAPHS + 1];

    // ---- wave 0: cooperative boundary search (33 targets, 22 probes) ----
    if (wid == 0) {
        const int tl     = (lane < B_GRAPHS) ? lane : B_GRAPHS;
        const int target = bg0 + tl;     // lower_bound target in [0, n_graphs]
        unsigned p2 = 1;
        while (p2 < (unsigned)n) p2 <<= 1;
        int bv = 0;
        for (unsigned step = p2 >> 1; step > 0; step >>= 1) {
            const unsigned cand = (unsigned)bv + step;
            if (cand <= (unsigned)n && batch[cand - 1] < target) bv = (int)cand;
        }
        // lower_bound for target==n_graphs lands at n (batch values < n_graphs)
        if (lane <= B_GRAPHS) sbnd[lane] = bv;
    }
    __syncthreads();

    // ---- uniform weight prep ----
    const float kA0 = w_tp[0] * INV_SQRT2;
    const float kA1 = w_tp[1] * INV_SQRT2;
    const float kB0 = w_tp[2] * (INV_SQRT3 * INV_SQRT2);
    const float kB1 = w_tp[3] * (INV_SQRT3 * INV_SQRT2);
    const float c0  = (w_tp[4] + w_tp[6]) * INV_SQRT2;
    const float c1  = (w_tp[5] + w_tp[7]) * INV_SQRT2;
    const float wE  = w_tp[8];
    const float fw0 = fc_w[0], fw1 = fc_w[1];
    const float fb  = fc_b[0];

    const float P0 = gate_p(c0, fc_w[2]) + gate_p(c1, fc_w[5]);
    const float N0 = gate_n(c0, fc_w[2]) + gate_n(c1, fc_w[5]);
    const float P1 = gate_p(c0, fc_w[3]) + gate_p(c1, fc_w[6]);
    const float N1 = gate_n(c0, fc_w[3]) + gate_n(c1, fc_w[6]);
    const float P2 = gate_p(c0, fc_w[4]) + gate_p(c1, fc_w[7]);
    const float N2 = gate_n(c0, fc_w[4]) + gate_n(c1, fc_w[7]);
    const float k8  = wE * SQRT2,     k11 = wE * INV_SQRT2, k12 = wE * INV_SQRT6;
    const float P8  = gate_p(k8,  fc_w[8]),  N8  = gate_n(k8,  fc_w[8]);
    const float P9  = gate_p(k8,  fc_w[9]),  N9  = gate_n(k8,  fc_w[9]);
    const float P10 = gate_p(k8,  fc_w[10]), N10 = gate_n(k8,  fc_w[10]);
    const float P11 = gate_p(k11, fc_w[11]), N11 = gate_n(k11, fc_w[11]);
    const float P12 = gate_p(k12, fc_w[12]), N12 = gate_n(k12, fc_w[12]);

    // ---- this wave's 9 boundaries from LDS (broadcast reads) ----
    const int wb   = wid * W_GRAPHS;
    const int B0 = sbnd[wb + 0], B1 = sbnd[wb + 1];
    const int B2 = sbnd[wb + 2], B3 = sbnd[wb + 3];
    const int B4 = sbnd[wb + 4], B5 = sbnd[wb + 5];
    const int B6 = sbnd[wb + 6], B7 = sbnd[wb + 7];
    const int B8 = sbnd[wb + 8];
    // per-lane pair for the final count (lane<8)
    const int myb = sbnd[wb + ((lane < W_GRAPHS) ? lane : W_GRAPHS)];
    const int nbv = sbnd[wb + ((lane < W_GRAPHS) ? lane + 1 : W_GRAPHS)];

    float a0 = 0.f, a1 = 0.f, a2 = 0.f, a3 = 0.f;
    float a4 = 0.f, a5 = 0.f, a6 = 0.f, a7 = 0.f;

#pragma unroll 1
    for (int base = B0; base < B8; base += 64) {
        const int i = base + lane;
        if (i < B8) {
            const float sc = (float)z[i];
            const float v0 = pos[i * 3 + 0];
            const float v1 = pos[i * 3 + 1];
            const float v2 = pos[i * 3 + 2];

            const float v00 = v0 * v0, v11 = v1 * v1, v22 = v2 * v2;
            const float ss  = sc * sc;
            const float dr  = v00 + v11 + v22;

            float acc = fb;
            const float x0 = fmaf(ss, kA0, dr * kB0);
            const float x1 = fmaf(ss, kA1, dr * kB1);
            acc = fmaf(fmaxf(x0, 0.f), fw0, acc);
            acc = fmaf(fmaxf(x1, 0.f), fw1, acc);

            const float sv0 = sc * v0, sv1 = sc * v1, sv2 = sc * v2;
            acc = fmaf(sv0, (sv0 > 0.f ? P0 : N0), acc);
            acc = fmaf(sv1, (sv1 > 0.f ? P1 : N1), acc);
            acc = fmaf(sv2, (sv2 > 0.f ? P2 : N2), acc);

            const float t8 = v0 * v1, t9 = v1 * v2, t10 = v0 * v2;
            acc = fmaf(t8,  (t8  > 0.f ? P8  : N8 ), acc);
            acc = fmaf(t9,  (t9  > 0.f ? P9  : N9 ), acc);
            acc = fmaf(t10, (t10 > 0.f ? P10 : N10), acc);

            const float t11 = v00 - v11;
            acc = fmaf(t11, (t11 > 0.f ? P11 : N11), acc);
            const float t12 = (v22 - v00) + (v22 - v11);
            acc = fmaf(t12, (t12 > 0.f ? P12 : N12), acc);

            const float y = fast_tanh(acc);

            const bool ge1 = i >= B1, ge2 = i >= B2, ge3 = i >= B3;
            const bool ge4 = i >= B4, ge5 = i >= B5, ge6 = i >= B6;
            const bool ge7 = i >= B7;
            a0 += (!ge1)        ? y : 0.f;
            a1 += (ge1 && !ge2) ? y : 0.f;
            a2 += (ge2 && !ge3) ? y : 0.f;
            a3 += (ge3 && !ge4) ? y : 0.f;
            a4 += (ge4 && !ge5) ? y : 0.f;
            a5 += (ge5 && !ge6) ? y : 0.f;
            a6 += (ge6 && !ge7) ? y : 0.f;
            a7 += (ge7)         ? y : 0.f;
        }
    }

    // butterfly reduction (converged)
#pragma unroll
    for (int off = 32; off >= 1; off >>= 1) {
        a0 += __shfl_xor(a0, off);
        a1 += __shfl_xor(a1, off);
        a2 += __shfl_xor(a2, off);
        a3 += __shfl_xor(a3, off);
        a4 += __shfl_xor(a4, off);
        a5 += __shfl_xor(a5, off);
        a6 += __shfl_xor(a6, off);
        a7 += __shfl_xor(a7, off);
    }

    const int gw0 = bg0 + wid * W_GRAPHS;
    if (lane < W_GRAPHS && gw0 + lane < n_graphs) {
        float sel = (lane == 0) ? a0
                  : (lane == 1) ? a1
                  : (lane == 2) ? a2
                  : (lane == 3) ? a3
                  : (lane == 4) ? a4
                  : (lane == 5) ? a5
                  : (lane == 6) ? a6
                  :               a7;
        const float c = (float)(nbv - myb);
        out[gw0 + lane] = sel / fmaxf(c, 1.0f);
    }
}

extern "C" void kernel_launch(void* const* d_in, const int* in_sizes, int n_in,
                              void* d_out, int out_size, void* d_ws, size_t ws_size,
                              hipStream_t stream) {
    const int*   z     = (const int*)d_in[0];
    const float* pos   = (const float*)d_in[1];
    const int*   batch = (const int*)d_in[2];
    const float* w_tp  = (const float*)d_in[3];
    const float* fc_w  = (const float*)d_in[4];
    const float* fc_b  = (const float*)d_in[5];

    float* out = (float*)d_out;
    const int n        = in_sizes[0];
    const int n_graphs = out_size;

    const int blocks = (n_graphs + B_GRAPHS - 1) / B_GRAPHS;
    e3nn_fused<<<blocks, 256, 0, stream>>>(z, pos, batch, w_tp, fc_w, fc_b,
                                           out, n, n_graphs);
}